// Round 11
// baseline (178.424 us; speedup 1.0000x reference)
//
#include <hip/hip_runtime.h>

typedef __attribute__((ext_vector_type(8))) short short8;
typedef __attribute__((ext_vector_type(4))) float f32x4;

#define INF 4096
#define NKT 40              // 5 chunks * 8 K-tiles of 32
#define BUFB 16384          // per K-tile buffer: A[128][32] 8KB + B[128][32] 8KB

#define AS1 __attribute__((address_space(1)))
#define AS3 __attribute__((address_space(3)))

__device__ __forceinline__ unsigned short f2bf(float f) {
    unsigned int u = __float_as_uint(f);
    u += 0x7FFFu + ((u >> 16) & 1u);
    return (unsigned short)(u >> 16);
}

__device__ __forceinline__ void gl_lds16(const unsigned short* g, void* l) {
    __builtin_amdgcn_global_load_lds((const AS1 void*)g, (AS3 void*)l, 16, 0, 0);
}

// swizzle within [128][64B] regions: XOR byte bits {4,5} with row bits {1,2}.
// Involution, 16B-preserving; fragment reads measured 0 conflicts (R4/R5).
__device__ __forceinline__ int swz6(int b) { return b ^ ((b >> 3) & 0x30); }

#define BAR()   __builtin_amdgcn_s_barrier()
#define SB0()   __builtin_amdgcn_sched_barrier(0)

// ---------------- prepass: fp32 -> bf16 for x and hw ----------------
__global__ __launch_bounds__(256)
void cvt_bf16(const float* __restrict__ x, const float* __restrict__ hw,
              unsigned short* __restrict__ xb, unsigned short* __restrict__ wb)
{
    const long long NX = 8192LL * 4096;
    const long long NW = 5LL * 16 * 256 * 256;
    const long long total8 = (NX + NW) / 8;
    for (long long i = (long long)blockIdx.x * 256 + threadIdx.x; i < total8;
         i += (long long)gridDim.x * 256) {
        long long e = i * 8;
        const float* src;
        unsigned short* dst;
        long long off;
        if (e < NX) { src = x;  dst = xb; off = e; }
        else        { src = hw; dst = wb; off = e - NX; }
        float4 f0 = *(const float4*)(src + off);
        float4 f1 = *(const float4*)(src + off + 4);
        ushort4 u0, u1;
        u0.x = f2bf(f0.x); u0.y = f2bf(f0.y); u0.z = f2bf(f0.z); u0.w = f2bf(f0.w);
        u1.x = f2bf(f1.x); u1.y = f2bf(f1.y); u1.z = f2bf(f1.z); u1.w = f2bf(f1.w);
        *(ushort4*)(dst + off)     = u0;
        *(ushort4*)(dst + off + 4) = u1;
    }
}

// ===== main GEMM: 128x128 tile (m97-best), 4 waves (2x2), BK=32, 3-buffer, =====
// ===== XCD-chunked grid.  3 blocks/CU target: LDS 48KB, <=170 VGPR.       =====
__global__ __launch_bounds__(256, 3)
void hcl_g128(const unsigned short* __restrict__ xb,
              const unsigned short* __restrict__ wb,
              const float* __restrict__ hb,
              float* __restrict__ out)
{
    __shared__ char lds[3 * BUFB];

    const int tid  = threadIdx.x;        // 0..255
    const int lane = tid & 63;
    const int wave = tid >> 6;           // 0..3
    const int wr   = wave >> 1;          // m-half of 128
    const int wc   = wave & 1;           // n-half of 128
    const int ln15 = lane & 15;
    const int hi   = lane >> 4;          // 0..3

    // XCD-bijective swizzle (2048 % 8 == 0): each XCD gets 256 consecutive
    // work-ids = 4 (p,nh)-columns = 2 full p-columns -> B panel L2-resident.
    const int newid = (blockIdx.x & 7) * 256 + (blockIdx.x >> 3);
    const int col_i = newid >> 6;        // 0..31 = (p,nh) column
    const int bm0   = (newid & 63) * 128;
    const int p     = col_i >> 1;
    const int nh    = col_i & 1;

    // fragment byte offsets within a 16KB buffer (A at 0, B at 8192)
    int offA[4], offB[4];
    #pragma unroll
    for (int mf = 0; mf < 4; ++mf)
        offA[mf] = swz6((wr * 64 + mf * 16 + ln15) * 64 + hi * 16);
    #pragma unroll
    for (int nf = 0; nf < 4; ++nf)
        offB[nf] = 8192 + swz6((wc * 64 + nf * 16 + ln15) * 64 + hi * 16);

    // staging source geometry: inst j writes phys = j*4096 + tid*16 (linear
    // within an 8KB region); logical = swz6(phys) -> (row, kcol)
    int rj[2], cj[2];
    #pragma unroll
    for (int j = 0; j < 2; ++j) {
        int L = swz6(j * 4096 + tid * 16);
        rj[j] = L >> 6;
        cj[j] = (L & 63) >> 1;
    }

    f32x4 acc[4][4] = {};

    auto STAGE = [&](int kt, int buf) {
        if (kt >= NKT) return;
        const int t  = kt >> 3;
        const int s  = p ^ ((1 << t) >> 1);
        const int k0 = (kt & 7) * 32;
        const unsigned short* ga = xb + (size_t)bm0 * INF + s * 256 + k0;
        const unsigned short* gb = wb + ((size_t)(t * 16 + s) << 16) + nh * 128 * 256 + k0;
        char* lb = lds + buf * BUFB + tid * 16;
        gl_lds16(ga + (size_t)rj[0] * INF + cj[0], lb);
        gl_lds16(ga + (size_t)rj[1] * INF + cj[1], lb + 4096);
        gl_lds16(gb + (size_t)rj[0] * 256 + cj[0], lb + 8192);
        gl_lds16(gb + (size_t)rj[1] * 256 + cj[1], lb + 8192 + 4096);
    };

    auto COMPUTE = [&](int buf) {
        const char* L = lds + buf * BUFB;
        short8 fa[4], fb[4];
        #pragma unroll
        for (int nf = 0; nf < 4; ++nf) fb[nf] = *(const short8*)(L + offB[nf]);
        #pragma unroll
        for (int mf = 0; mf < 4; ++mf) fa[mf] = *(const short8*)(L + offA[mf]);
        __builtin_amdgcn_s_setprio(1);
        #pragma unroll
        for (int mi = 0; mi < 4; ++mi)
            #pragma unroll
            for (int nj = 0; nj < 4; ++nj)
                acc[mi][nj] = __builtin_amdgcn_mfma_f32_16x16x32_bf16(
                    fa[mi], fb[nj], acc[mi][nj], 0, 0, 0);
        __builtin_amdgcn_s_setprio(0);
    };

    // prologue: tiles 0,1 in flight
    STAGE(0, 0);
    STAGE(1, 1);
    // main loop: stage kt+2, gate kt (vmcnt 8 = tiles kt+1,kt+2 in flight)
    for (int kt = 0; kt < NKT - 2; ++kt) {
        STAGE(kt + 2, (kt + 2) % 3);
        asm volatile("s_waitcnt vmcnt(8)" ::: "memory");
        BAR(); SB0();
        COMPUTE(kt % 3);
        BAR(); SB0();
    }
    asm volatile("s_waitcnt vmcnt(4)" ::: "memory");
    BAR(); SB0();
    COMPUTE((NKT - 2) % 3);
    BAR(); SB0();
    asm volatile("s_waitcnt vmcnt(0)" ::: "memory");
    BAR(); SB0();
    COMPUTE((NKT - 1) % 3);

    // epilogue: C/D layout col = lane&15, row = (lane>>4)*4 + r  [verified]
    const int col0 = p * 256 + nh * 128 + wc * 64;
    #pragma unroll
    for (int nj = 0; nj < 4; ++nj) {
        const int col = col0 + nj * 16 + ln15;
        const float bias = hb[col];
        #pragma unroll
        for (int mi = 0; mi < 4; ++mi) {
            #pragma unroll
            for (int r = 0; r < 4; ++r) {
                const int row = bm0 + wr * 64 + mi * 16 + hi * 4 + r;
                out[(size_t)row * 4096 + col] = acc[mi][nj][r] + bias;
            }
        }
    }
}

// ---------------- fallback (fused) if ws too small ----------------
__global__ __launch_bounds__(256)
void hcl_mfma_fused(const float* __restrict__ x,
                    const float* __restrict__ hw,
                    const float* __restrict__ hb,
                    float* __restrict__ out)
{
    __shared__ unsigned short As[128][32];
    __shared__ unsigned short Bs[128][32];

    const int tid  = threadIdx.x;
    const int lane = tid & 63;
    const int wave = tid >> 6;
    const int wr   = wave >> 1, wc = wave & 1;

    const int bm0 = blockIdx.x * 128;
    const int p   = blockIdx.y >> 1;
    const int nh  = blockIdx.y & 1;

    f32x4 acc[4][4] = {};

    const int srow = tid >> 3;
    const int scol = (tid & 7) * 4;

    #pragma unroll
    for (int t = 0; t < 5; ++t) {
        const int mask = (t == 0) ? 0 : (1 << (t - 1));
        const int s = p ^ mask;
        const float* xchunk = x  + (size_t)bm0 * INF + s * 256;
        const float* wchunk = hw + ((size_t)(t * 16 + s) * 256 + nh * 128) * 256;

        for (int k8 = 0; k8 < 8; ++k8) {
            const int kc = k8 * 32;
            #pragma unroll
            for (int i = 0; i < 4; ++i) {
                const int row = i * 32 + srow;
                float4 fa = *(const float4*)(xchunk + (size_t)row * INF + kc + scol);
                float4 fb = *(const float4*)(wchunk + (size_t)row * 256 + kc + scol);
                ushort4 ua, ub;
                ua.x = f2bf(fa.x); ua.y = f2bf(fa.y);
                ua.z = f2bf(fa.z); ua.w = f2bf(fa.w);
                ub.x = f2bf(fb.x); ub.y = f2bf(fb.y);
                ub.z = f2bf(fb.z); ub.w = f2bf(fb.w);
                *(ushort4*)&As[row][scol] = ua;
                *(ushort4*)&Bs[row][scol] = ub;
            }
            __syncthreads();

            short8 a[4], b[4];
            #pragma unroll
            for (int mi = 0; mi < 4; ++mi)
                a[mi] = *(const short8*)&As[wr * 64 + mi * 16 + (lane & 15)][(lane >> 4) * 8];
            #pragma unroll
            for (int nj = 0; nj < 4; ++nj)
                b[nj] = *(const short8*)&Bs[wc * 64 + nj * 16 + (lane & 15)][(lane >> 4) * 8];

            #pragma unroll
            for (int mi = 0; mi < 4; ++mi)
                #pragma unroll
                for (int nj = 0; nj < 4; ++nj)
                    acc[mi][nj] = __builtin_amdgcn_mfma_f32_16x16x32_bf16(
                        a[mi], b[nj], acc[mi][nj], 0, 0, 0);

            __syncthreads();
        }
    }

    const int col0 = p * 256 + nh * 128 + wc * 64;
    #pragma unroll
    for (int nj = 0; nj < 4; ++nj) {
        const int col = col0 + nj * 16 + (lane & 15);
        const float bias = hb[col];
        #pragma unroll
        for (int mi = 0; mi < 4; ++mi) {
            #pragma unroll
            for (int r = 0; r < 4; ++r) {
                const int row = bm0 + wr * 64 + mi * 16 + (lane >> 4) * 4 + r;
                out[(size_t)row * 4096 + col] = acc[mi][nj][r] + bias;
            }
        }
    }
}

extern "C" void kernel_launch(void* const* d_in, const int* in_sizes, int n_in,
                              void* d_out, int out_size, void* d_ws, size_t ws_size,
                              hipStream_t stream) {
    const float* x  = (const float*)d_in[0];   // [8192, 4096]
    const float* hw = (const float*)d_in[1];   // [5, 16, 256, 256]
    const float* hb = (const float*)d_in[2];   // [4096]
    float* out = (float*)d_out;                // [8192, 4096]

    const size_t NX = 8192ull * 4096;
    const size_t NW = 5ull * 16 * 256 * 256;
    const size_t need = (NX + NW) * sizeof(unsigned short);

    if (ws_size >= need) {
        unsigned short* xb = (unsigned short*)d_ws;
        unsigned short* wb = xb + NX;
        cvt_bf16<<<2048, 256, 0, stream>>>(x, hw, xb, wb);
        hcl_g128<<<2048, 256, 0, stream>>>(xb, wb, hb, out);
    } else {
        dim3 grid(8192 / 128, 32);
        hcl_mfma_fused<<<grid, 256, 0, stream>>>(x, hw, hb, out);
    }
}

// Round 12
// 167.638 us; speedup vs baseline: 1.0643x; 1.0643x over previous
//
#include <hip/hip_runtime.h>

typedef __attribute__((ext_vector_type(8))) short short8;
typedef __attribute__((ext_vector_type(4))) float f32x4;

#define INF 4096

#define AS1 __attribute__((address_space(1)))
#define AS3 __attribute__((address_space(3)))

__device__ __forceinline__ unsigned short f2bf(float f) {
    unsigned int u = __float_as_uint(f);
    u += 0x7FFFu + ((u >> 16) & 1u);
    return (unsigned short)(u >> 16);
}

__device__ __forceinline__ unsigned int pkbf(float a, float b) {
    unsigned int r;
    asm volatile("v_cvt_pk_bf16_f32 %0, %1, %2" : "=v"(r) : "v"(a), "v"(b));
    return r;   // lo16 = bf16(a), hi16 = bf16(b)  (RNE)
}

__device__ __forceinline__ void gl_lds16(const unsigned short* g, void* l) {
    __builtin_amdgcn_global_load_lds((const AS1 void*)g, (AS3 void*)l, 16, 0, 0);
}

// swizzle within a 16KB region [128 rows][64 bf16] (128B rows): XOR byte bits
// {4,5,6} with row bits {0,1,2} (byte bits 7,8,9). Involution, 16B-preserving,
// row-preserving (bits>=7 untouched). Fragment reads: 0 conflicts (R8/R9).
__device__ __forceinline__ int swz7(int b) { return b ^ ((b >> 3) & 0x70); }

#define BAR()   __builtin_amdgcn_s_barrier()
#define SB0()   __builtin_amdgcn_sched_barrier(0)

// ---------------- tiny prepass: fp32 -> bf16 for hw only (10.5 MB) ----------------
__global__ __launch_bounds__(256)
void cvt_w(const float* __restrict__ hw, unsigned short* __restrict__ wb)
{
    const long long NW8 = (5LL * 16 * 256 * 256) / 8;   // 655360
    for (long long i = (long long)blockIdx.x * 256 + threadIdx.x; i < NW8;
         i += (long long)gridDim.x * 256) {
        long long e = i * 8;
        float4 f0 = *(const float4*)(hw + e);
        float4 f1 = *(const float4*)(hw + e + 4);
        ushort4 u0, u1;
        u0.x = f2bf(f0.x); u0.y = f2bf(f0.y); u0.z = f2bf(f0.z); u0.w = f2bf(f0.w);
        u1.x = f2bf(f1.x); u1.y = f2bf(f1.y); u1.z = f2bf(f1.z); u1.w = f2bf(f1.w);
        *(ushort4*)(wb + e)     = u0;
        *(ushort4*)(wb + e + 4) = u1;
    }
}

// ======== fused GEMM: 128x128 tile, 4 waves (2x2), BK=64, 2-buffer ========
// A: x read as FP32 direct (no prepass) -> regs at iter top -> cvt_pk ->
//    ds_write_b128 (swz7 layout) at iter bottom. Landing slack = 1 compute
//    phase; cross-wave visibility via lgkmcnt(0)+barrier.
// B: bf16 wb via global_load_lds (R9-proven path, pre-swizzled source).
// LDS: 2 bufs x (A 16KB @0 + B 16KB @16384) = 64KB -> 2 blocks/CU.
__global__ __launch_bounds__(256, 2)
void hcl_f1(const float* __restrict__ x,
            const unsigned short* __restrict__ wb,
            const float* __restrict__ hb,
            float* __restrict__ out)
{
    __shared__ char lds[2 * 32768];

    const int tid  = threadIdx.x;        // 0..255
    const int lane = tid & 63;
    const int wave = tid >> 6;           // 0..3
    const int wr   = wave >> 1;          // m-half
    const int wc   = wave & 1;           // n-half
    const int ln15 = lane & 15;
    const int hi   = lane >> 4;

    const int bm0 = blockIdx.x * 128;
    const int p   = blockIdx.y >> 1;
    const int nh  = blockIdx.y & 1;

    // fragment byte offsets (ks=1 via ^64: bit6 not a swz7 source bit)
    int offA[4], offB[4];
    #pragma unroll
    for (int mf = 0; mf < 4; ++mf)
        offA[mf] = swz7((wr * 64 + mf * 16 + ln15) * 128 + hi * 16);
    #pragma unroll
    for (int nf = 0; nf < 4; ++nf)
        offB[nf] = 16384 + swz7((wc * 64 + nf * 16 + ln15) * 128 + hi * 16);

    // staging geometry round j (j=0..3): phys = j*4096 + tid*16 (linear);
    // row = j*32 + tid>>3 (swz7 row-preserving); col = swizzled 16B slot.
    const int srow0 = tid >> 3;                               // + j*32
    int scol[4];
    #pragma unroll
    for (int j = 0; j < 4; ++j)
        scol[j] = (swz7(j * 4096 + tid * 16) & 127) >> 1;     // bf16/K idx

    f32x4 acc[4][4] = {};

    auto BSTAGE = [&](int kt) {            // 4 x gl_lds into buf (kt&1) B-region
        if (kt >= 20) return;
        const int t  = kt >> 2;
        const int s  = p ^ ((1 << t) >> 1);
        const int k0 = (kt & 3) * 64;
        const unsigned short* gb = wb + ((size_t)(t * 16 + s) << 16)
                                      + (size_t)(nh * 128) * 256 + k0;
        char* db = lds + (kt & 1) * 32768 + 16384 + tid * 16;
        #pragma unroll
        for (int j = 0; j < 4; ++j)
            gl_lds16(gb + (size_t)(j * 32 + srow0) * 256 + scol[j], db + j * 4096);
    };

    float4 av[8];
    auto ALOAD = [&](int kt) {             // 8 x dwordx4 fp32 -> regs
        if (kt >= 20) return;
        const int t  = kt >> 2;
        const int s  = p ^ ((1 << t) >> 1);
        const int k0 = (kt & 3) * 64;
        const float* gx = x + (size_t)bm0 * INF + s * 256 + k0;
        #pragma unroll
        for (int j = 0; j < 4; ++j) {
            const float* src = gx + (size_t)(j * 32 + srow0) * INF + scol[j];
            av[j * 2 + 0] = *(const float4*)(src);
            av[j * 2 + 1] = *(const float4*)(src + 4);
        }
    };
    auto AWRITE = [&](int kt) {            // cvt_pk + 4 x ds_write_b128
        if (kt >= 20) return;
        char* da = lds + (kt & 1) * 32768 + tid * 16;
        #pragma unroll
        for (int j = 0; j < 4; ++j) {
            int4 u;
            u.x = (int)pkbf(av[j * 2 + 0].x, av[j * 2 + 0].y);
            u.y = (int)pkbf(av[j * 2 + 0].z, av[j * 2 + 0].w);
            u.z = (int)pkbf(av[j * 2 + 1].x, av[j * 2 + 1].y);
            u.w = (int)pkbf(av[j * 2 + 1].z, av[j * 2 + 1].w);
            *(int4*)(da + j * 4096) = u;
        }
    };

    auto COMPUTE = [&](int kt) {
        const char* L = lds + (kt & 1) * 32768;
        short8 fa[8], fb[8];
        #pragma unroll
        for (int nf = 0; nf < 4; ++nf) {
            fb[nf * 2 + 0] = *(const short8*)(L + offB[nf]);
            fb[nf * 2 + 1] = *(const short8*)(L + (offB[nf] ^ 64));
        }
        #pragma unroll
        for (int mf = 0; mf < 4; ++mf) {
            fa[mf * 2 + 0] = *(const short8*)(L + offA[mf]);
            fa[mf * 2 + 1] = *(const short8*)(L + (offA[mf] ^ 64));
        }
        __builtin_amdgcn_s_setprio(1);
        #pragma unroll
        for (int mi = 0; mi < 4; ++mi)
            #pragma unroll
            for (int nj = 0; nj < 4; ++nj)
                #pragma unroll
                for (int ks = 0; ks < 2; ++ks)
                    acc[mi][nj] = __builtin_amdgcn_mfma_f32_16x16x32_bf16(
                        fa[mi * 2 + ks], fb[nj * 2 + ks], acc[mi][nj], 0, 0, 0);
        __builtin_amdgcn_s_setprio(0);
    };

    // prologue: tile 0 staged (B via gl_lds, A via reg+cvt; AWRITE's reg use
    // auto-drains all VMEM). Visibility fenced by lgkm + the loop-top barrier.
    BSTAGE(0); ALOAD(0);
    AWRITE(0);
    asm volatile("s_waitcnt lgkmcnt(0)" ::: "memory");

    for (int kt = 0; kt < 20; ++kt) {
        // top: issue next tile's B gl_lds + A fp32 reg-loads (hide under compute)
        BSTAGE(kt + 1); ALOAD(kt + 1);
        BAR(); SB0();
        COMPUTE(kt);
        // bottom: convert+write A(kt+1); compiler's av-wait drains B(kt+1) too
        AWRITE(kt + 1);
        asm volatile("s_waitcnt lgkmcnt(0)" ::: "memory");
        BAR(); SB0();
    }

    // epilogue: C/D layout col = lane&15, row = (lane>>4)*4 + r  [verified]
    const int col0 = p * 256 + nh * 128 + wc * 64;
    #pragma unroll
    for (int nj = 0; nj < 4; ++nj) {
        const int col = col0 + nj * 16 + ln15;
        const float bias = hb[col];
        #pragma unroll
        for (int mi = 0; mi < 4; ++mi) {
            #pragma unroll
            for (int r = 0; r < 4; ++r) {
                const int row = bm0 + wr * 64 + mi * 16 + hi * 4 + r;
                out[(size_t)row * 4096 + col] = acc[mi][nj][r] + bias;
            }
        }
    }
}

// ---------------- fallback (fused fp32->bf16 inline) if ws too small ----------------
__global__ __launch_bounds__(256)
void hcl_mfma_fused(const float* __restrict__ x,
                    const float* __restrict__ hw,
                    const float* __restrict__ hb,
                    float* __restrict__ out)
{
    __shared__ unsigned short As[128][32];
    __shared__ unsigned short Bs[128][32];

    const int tid  = threadIdx.x;
    const int lane = tid & 63;
    const int wave = tid >> 6;
    const int wr   = wave >> 1, wc = wave & 1;

    const int bm0 = blockIdx.x * 128;
    const int p   = blockIdx.y >> 1;
    const int nh  = blockIdx.y & 1;

    f32x4 acc[4][4] = {};

    const int srow = tid >> 3;
    const int scol = (tid & 7) * 4;

    #pragma unroll
    for (int t = 0; t < 5; ++t) {
        const int mask = (t == 0) ? 0 : (1 << (t - 1));
        const int s = p ^ mask;
        const float* xchunk = x  + (size_t)bm0 * INF + s * 256;
        const float* wchunk = hw + ((size_t)(t * 16 + s) * 256 + nh * 128) * 256;

        for (int k8 = 0; k8 < 8; ++k8) {
            const int kc = k8 * 32;
            #pragma unroll
            for (int i = 0; i < 4; ++i) {
                const int row = i * 32 + srow;
                float4 fa = *(const float4*)(xchunk + (size_t)row * INF + kc + scol);
                float4 fb = *(const float4*)(wchunk + (size_t)row * 256 + kc + scol);
                ushort4 ua, ub;
                ua.x = f2bf(fa.x); ua.y = f2bf(fa.y);
                ua.z = f2bf(fa.z); ua.w = f2bf(fa.w);
                ub.x = f2bf(fb.x); ub.y = f2bf(fb.y);
                ub.z = f2bf(fb.z); ub.w = f2bf(fb.w);
                *(ushort4*)&As[row][scol] = ua;
                *(ushort4*)&Bs[row][scol] = ub;
            }
            __syncthreads();

            short8 a[4], b[4];
            #pragma unroll
            for (int mi = 0; mi < 4; ++mi)
                a[mi] = *(const short8*)&As[wr * 64 + mi * 16 + (lane & 15)][(lane >> 4) * 8];
            #pragma unroll
            for (int nj = 0; nj < 4; ++nj)
                b[nj] = *(const short8*)&Bs[wc * 64 + nj * 16 + (lane & 15)][(lane >> 4) * 8];

            #pragma unroll
            for (int mi = 0; mi < 4; ++mi)
                #pragma unroll
                for (int nj = 0; nj < 4; ++nj)
                    acc[mi][nj] = __builtin_amdgcn_mfma_f32_16x16x32_bf16(
                        a[mi], b[nj], acc[mi][nj], 0, 0, 0);

            __syncthreads();
        }
    }

    const int col0 = p * 256 + nh * 128 + wc * 64;
    #pragma unroll
    for (int nj = 0; nj < 4; ++nj) {
        const int col = col0 + nj * 16 + (lane & 15);
        const float bias = hb[col];
        #pragma unroll
        for (int mi = 0; mi < 4; ++mi) {
            #pragma unroll
            for (int r = 0; r < 4; ++r) {
                const int row = bm0 + wr * 64 + mi * 16 + (lane >> 4) * 4 + r;
                out[(size_t)row * 4096 + col] = acc[mi][nj][r] + bias;
            }
        }
    }
}

extern "C" void kernel_launch(void* const* d_in, const int* in_sizes, int n_in,
                              void* d_out, int out_size, void* d_ws, size_t ws_size,
                              hipStream_t stream) {
    const float* x  = (const float*)d_in[0];   // [8192, 4096]
    const float* hw = (const float*)d_in[1];   // [5, 16, 256, 256]
    const float* hb = (const float*)d_in[2];   // [4096]
    float* out = (float*)d_out;                // [8192, 4096]

    const size_t NW = 5ull * 16 * 256 * 256;
    const size_t need = NW * sizeof(unsigned short);   // 10.5 MB

    if (ws_size >= need) {
        unsigned short* wbuf = (unsigned short*)d_ws;
        cvt_w<<<1024, 256, 0, stream>>>(hw, wbuf);
        dim3 grid(8192 / 128, 32);
        hcl_f1<<<grid, 256, 0, stream>>>(x, wbuf, hb, out);
    } else {
        dim3 grid(8192 / 128, 32);
        hcl_mfma_fused<<<grid, 256, 0, stream>>>(x, hw, hb, out);
    }
}

// Round 13
// 153.675 us; speedup vs baseline: 1.1611x; 1.0909x over previous
//
#include <hip/hip_runtime.h>

typedef __attribute__((ext_vector_type(8))) short short8;
typedef __attribute__((ext_vector_type(4))) float f32x4;

#define INF 4096

#define AS1 __attribute__((address_space(1)))
#define AS3 __attribute__((address_space(3)))

__device__ __forceinline__ unsigned short f2bf(float f) {
    unsigned int u = __float_as_uint(f);
    u += 0x7FFFu + ((u >> 16) & 1u);
    return (unsigned short)(u >> 16);
}

__device__ __forceinline__ void gl_lds16(const unsigned short* g, void* l) {
    __builtin_amdgcn_global_load_lds((const AS1 void*)g, (AS3 void*)l, 16, 0, 0);
}

// swizzle within 1KB blocks: XOR byte bits {4,5,6} with bits {7,8,9}.
// Involution, 16B-preserving. For [128][64]bf16 regions (128B rows) this
// spreads the stride-128B fragment reads across the row. R8/R9-verified (0 confl).
__device__ __forceinline__ int swz7(int b) { return b ^ ((b >> 3) & 0x70); }
// 64B-row variant used by the fallback kernel (R4/R5-verified)
__device__ __forceinline__ int swz6(int b) { return b ^ ((b >> 3) & 0x30); }

#define BAR()   __builtin_amdgcn_s_barrier()
#define SB0()   __builtin_amdgcn_sched_barrier(0)

// ---------------- prepass: fp32 -> bf16 for x and hw ----------------
__global__ __launch_bounds__(256)
void cvt_bf16(const float* __restrict__ x, const float* __restrict__ hw,
              unsigned short* __restrict__ xb, unsigned short* __restrict__ wb)
{
    const long long NX = 8192LL * 4096;
    const long long NW = 5LL * 16 * 256 * 256;
    const long long total8 = (NX + NW) / 8;
    for (long long i = (long long)blockIdx.x * 256 + threadIdx.x; i < total8;
         i += (long long)gridDim.x * 256) {
        long long e = i * 8;
        const float* src;
        unsigned short* dst;
        long long off;
        if (e < NX) { src = x;  dst = xb; off = e; }
        else        { src = hw; dst = wb; off = e - NX; }
        float4 f0 = *(const float4*)(src + off);
        float4 f1 = *(const float4*)(src + off + 4);
        ushort4 u0, u1;
        u0.x = f2bf(f0.x); u0.y = f2bf(f0.y); u0.z = f2bf(f0.z); u0.w = f2bf(f0.w);
        u1.x = f2bf(f1.x); u1.y = f2bf(f1.y); u1.z = f2bf(f1.z); u1.w = f2bf(f1.w);
        *(ushort4*)(dst + off)     = u0;
        *(ushort4*)(dst + off + 4) = u1;
    }
}

// ======== main GEMM: 256x256 tile, 8 waves, BK=64, 2-buffer counted vmcnt ========
// Best measured structure (R9: 110 us, 781 TF). Per K-tile: one stage burst
// (8 gl_lds), one vmcnt(8) gate (next tile stays in flight; landing slack =
// a full compute phase), 2 barriers, compiler-scheduled compute (24 ds_read_b128
// + 64 MFMA per wave). LDS: 2 bufs x 64KB; regions per buf: 0=A rows0-127,
// 1=A rows128-255, 2=B cols0-127, 3=B cols128-255; each [128][64]bf16 swz7.
__global__ __launch_bounds__(512, 2)
void hcl_gemm64(const unsigned short* __restrict__ xb,
                const unsigned short* __restrict__ wb,
                const float* __restrict__ hb,
                float* __restrict__ out)
{
    extern __shared__ char lds[];   // 131072

    const int tid  = threadIdx.x;       // 0..511
    const int lane = tid & 63;
    const int wave = tid >> 6;          // 0..7
    const int wr   = wave >> 2;         // 0..1  m-half
    const int wcn  = wave & 3;          // 0..3  n-quarter
    const int ln15 = lane & 15;
    const int hi   = lane >> 4;

    const int bm0 = blockIdx.x * 256;
    const int p   = blockIdx.y;

    // fragment byte offsets within a buffer (ks=0; ks=1 is ^64: bit6 is not a
    // swz7 source bit, so swz7(x+64)=swz7(x)^64) [R8/R9-verified]
    int offA[8], offB[4];
    #pragma unroll
    for (int mf = 0; mf < 8; ++mf)
        offA[mf] = wr * 16384 + swz7((mf * 16 + ln15) * 128 + hi * 16);
    #pragma unroll
    for (int nf = 0; nf < 4; ++nf)
        offB[nf] = 32768 + (wcn >> 1) * 16384 +
                   swz7(((wcn & 1) * 64 + nf * 16 + ln15) * 128 + hi * 16);

    // staging source geometry: inst j writes phys = j*8192 + tid*16 (linear),
    // global source element = logical swz7(phys) within the 16KB region
    int srow[2], skcol[2];
    #pragma unroll
    for (int j = 0; j < 2; ++j) {
        int L = swz7(j * 8192 + tid * 16);
        srow[j]  = L >> 7;
        skcol[j] = (L & 127) >> 1;
    }

    f32x4 acc[8][4] = {};

    auto STAGE = [&](int kt, int reg) {   // reg: 0=A0,1=A1,2=B0,3=B1
        if (kt >= 20) return;
        const int t  = kt >> 2;
        const int s  = p ^ ((1 << t) >> 1);
        const int k0 = (kt & 3) * 64;
        char* dst = lds + (kt & 1) * 65536 + reg * 16384 + tid * 16;
        if (reg < 2) {
            const unsigned short* g = xb + (size_t)(bm0 + reg * 128) * INF + s * 256 + k0;
            gl_lds16(g + (size_t)srow[0] * INF + skcol[0], dst);
            gl_lds16(g + (size_t)srow[1] * INF + skcol[1], dst + 8192);
        } else {
            const unsigned short* g = wb + ((size_t)(t * 16 + s) << 16) + (reg - 2) * 32768 + k0;
            gl_lds16(g + (size_t)srow[0] * 256 + skcol[0], dst);
            gl_lds16(g + (size_t)srow[1] * 256 + skcol[1], dst + 8192);
        }
    };

    short8 fa[8], fb0[4], fb1[4];
    auto LDA = [&](int qm, int buf) {      // 8 ds_read_b128 into fa (K=64)
        const char* L = lds + buf * 65536;
        #pragma unroll
        for (int m = 0; m < 4; ++m) {
            fa[m * 2 + 0] = *(const short8*)(L + offA[qm * 4 + m]);
            fa[m * 2 + 1] = *(const short8*)(L + (offA[qm * 4 + m] ^ 64));
        }
    };
    auto LDB0 = [&](int buf) {             // qn0 -> fb0
        const char* L = lds + buf * 65536;
        #pragma unroll
        for (int n = 0; n < 2; ++n) {
            fb0[n * 2 + 0] = *(const short8*)(L + offB[n]);
            fb0[n * 2 + 1] = *(const short8*)(L + (offB[n] ^ 64));
        }
    };
    auto LDB1 = [&](int buf) {             // qn1 -> fb1
        const char* L = lds + buf * 65536;
        #pragma unroll
        for (int n = 0; n < 2; ++n) {
            fb1[n * 2 + 0] = *(const short8*)(L + offB[2 + n]);
            fb1[n * 2 + 1] = *(const short8*)(L + (offB[2 + n] ^ 64));
        }
    };
    auto MM0 = [&](int qm) {               // quadrant (qm, qn0) with fb0
        __builtin_amdgcn_s_setprio(1);
        #pragma unroll
        for (int m = 0; m < 4; ++m)
            #pragma unroll
            for (int n = 0; n < 2; ++n)
                #pragma unroll
                for (int ks = 0; ks < 2; ++ks)
                    acc[qm * 4 + m][n] = __builtin_amdgcn_mfma_f32_16x16x32_bf16(
                        fa[m * 2 + ks], fb0[n * 2 + ks], acc[qm * 4 + m][n], 0, 0, 0);
        __builtin_amdgcn_s_setprio(0);
    };
    auto MM1 = [&](int qm) {               // quadrant (qm, qn1) with fb1
        __builtin_amdgcn_s_setprio(1);
        #pragma unroll
        for (int m = 0; m < 4; ++m)
            #pragma unroll
            for (int n = 0; n < 2; ++n)
                #pragma unroll
                for (int ks = 0; ks < 2; ++ks)
                    acc[qm * 4 + m][2 + n] = __builtin_amdgcn_mfma_f32_16x16x32_bf16(
                        fa[m * 2 + ks], fb1[n * 2 + ks], acc[qm * 4 + m][2 + n], 0, 0, 0);
        __builtin_amdgcn_s_setprio(0);
    };

    // prologue: T0 -> buf0 (8 loads)
    STAGE(0, 0); STAGE(0, 1); STAGE(0, 2); STAGE(0, 3);

    for (int kt = 0; kt < 20; ++kt) {
        // stage next tile into the other buffer (kt=19 -> guarded no-op)
        STAGE(kt + 1, 0); STAGE(kt + 1, 1); STAGE(kt + 1, 2); STAGE(kt + 1, 3);
        // gate: current tile landed; next tile's 8 loads stay in flight
        if (kt < 19) { asm volatile("s_waitcnt vmcnt(8)" ::: "memory"); }
        else         { asm volatile("s_waitcnt vmcnt(0)" ::: "memory"); }
        BAR(); SB0();
        // compute K=64 on current buffer; compiler schedules ds_read<->MFMA
        const int buf = kt & 1;
        LDB0(buf); LDB1(buf); LDA(0, buf);
        MM0(0); MM1(0);
        LDA(1, buf);
        MM1(1); MM0(1);
        BAR(); SB0();
    }

    // epilogue: C/D layout col = lane&15, row = (lane>>4)*4 + r  [verified]
    const int col0 = p * 256 + wcn * 64;
    #pragma unroll
    for (int nf = 0; nf < 4; ++nf) {
        const int col = col0 + nf * 16 + ln15;
        const float bias = hb[col];
        #pragma unroll
        for (int mf = 0; mf < 8; ++mf) {
            #pragma unroll
            for (int r = 0; r < 4; ++r) {
                const int row = bm0 + wr * 128 + mf * 16 + hi * 4 + r;
                out[(size_t)row * 4096 + col] = acc[mf][nf][r] + bias;
            }
        }
    }
}

// -------- fallback GEMM (R5, proven): 128x256 tile, 4 waves, 3-buffer --------
#define NKT4 40
#define BUFB4 24576
__global__ __launch_bounds__(256, 2)
void hcl_gemm4(const unsigned short* __restrict__ xb,
               const unsigned short* __restrict__ wb,
               const float* __restrict__ hb,
               float* __restrict__ out)
{
    extern __shared__ unsigned short lds4[];

    const int tid  = threadIdx.x;
    const int lane = tid & 63;
    const int wave = tid >> 6;
    const int ln15 = lane & 15;
    const int hi   = lane >> 4;

    const int bm0 = blockIdx.x * 128;
    const int p   = blockIdx.y;

    int rj[4], cj[4];
    #pragma unroll
    for (int j = 0; j < 4; ++j) {
        int g = swz6(j * 4096 + tid * 16);
        rj[j] = g >> 6;
        cj[j] = (g & 63) >> 1;
    }

    int offA[8], offB[4];
    #pragma unroll
    for (int mf = 0; mf < 8; ++mf)
        offA[mf] = swz6((mf * 16 + ln15) * 64 + hi * 16);
    #pragma unroll
    for (int nf = 0; nf < 4; ++nf)
        offB[nf] = swz6((wave * 64 + nf * 16 + ln15) * 64 + hi * 16);

    f32x4 acc[8][4] = {};

    auto STAGE = [&](int kt, int buf) {
        const int t = kt >> 3;
        const int s = p ^ ((1 << t) >> 1);
        const unsigned short* ga = xb + (size_t)bm0 * INF + s * 256 + (kt & 7) * 32;
        const unsigned short* gb = wb + ((size_t)(t * 16 + s) << 16) + (kt & 7) * 32;
        char* lb = (char*)lds4 + buf * BUFB4 + wave * 1024;
        gl_lds16(ga + (size_t)rj[0] * INF + cj[0], lb);
        gl_lds16(ga + (size_t)rj[1] * INF + cj[1], lb + 4096);
        gl_lds16(gb + (size_t)rj[0] * 256 + cj[0], lb + 8192);
        gl_lds16(gb + (size_t)rj[1] * 256 + cj[1], lb + 8192 + 4096);
        gl_lds16(gb + (size_t)rj[2] * 256 + cj[2], lb + 8192 + 8192);
        gl_lds16(gb + (size_t)rj[3] * 256 + cj[3], lb + 8192 + 12288);
    };

    auto COMPUTE = [&](int buf) {
        const char* LA = (const char*)lds4 + buf * BUFB4;
        const char* LB = LA + 8192;
        short8 fa[8], fb[4];
        #pragma unroll
        for (int nf = 0; nf < 4; ++nf) fb[nf] = *(const short8*)(LB + offB[nf]);
        #pragma unroll
        for (int mf = 0; mf < 8; ++mf) fa[mf] = *(const short8*)(LA + offA[mf]);
        __builtin_amdgcn_s_setprio(1);
        #pragma unroll
        for (int mf = 0; mf < 8; ++mf)
            #pragma unroll
            for (int nf = 0; nf < 4; ++nf)
                acc[mf][nf] = __builtin_amdgcn_mfma_f32_16x16x32_bf16(
                    fa[mf], fb[nf], acc[mf][nf], 0, 0, 0);
        __builtin_amdgcn_s_setprio(0);
    };

    STAGE(0, 0);
    STAGE(1, 1);
    for (int kt = 0; kt < NKT4 - 2; ++kt) {
        STAGE(kt + 2, (kt + 2) % 3);
        asm volatile("s_waitcnt vmcnt(12)" ::: "memory");
        BAR(); SB0();
        COMPUTE(kt % 3);
        BAR(); SB0();
    }
    asm volatile("s_waitcnt vmcnt(6)" ::: "memory");
    BAR(); SB0();
    COMPUTE((NKT4 - 2) % 3);
    BAR(); SB0();
    asm volatile("s_waitcnt vmcnt(0)" ::: "memory");
    BAR(); SB0();
    COMPUTE((NKT4 - 1) % 3);

    const int col0 = p * 256 + wave * 64;
    #pragma unroll
    for (int nf = 0; nf < 4; ++nf) {
        const int col = col0 + nf * 16 + ln15;
        const float bias = hb[col];
        #pragma unroll
        for (int mf = 0; mf < 8; ++mf) {
            #pragma unroll
            for (int r = 0; r < 4; ++r) {
                const int row = bm0 + mf * 16 + hi * 4 + r;
                out[(size_t)row * 4096 + col] = acc[mf][nf][r] + bias;
            }
        }
    }
}

// ---------------- fallback (fused) if ws too small ----------------
__global__ __launch_bounds__(256)
void hcl_mfma_fused(const float* __restrict__ x,
                    const float* __restrict__ hw,
                    const float* __restrict__ hb,
                    float* __restrict__ out)
{
    __shared__ unsigned short As[128][32];
    __shared__ unsigned short Bs[128][32];

    const int tid  = threadIdx.x;
    const int lane = tid & 63;
    const int wave = tid >> 6;
    const int wr   = wave >> 1, wc = wave & 1;

    const int bm0 = blockIdx.x * 128;
    const int p   = blockIdx.y >> 1;
    const int nh  = blockIdx.y & 1;

    f32x4 acc[4][4] = {};

    const int srow = tid >> 3;
    const int scol = (tid & 7) * 4;

    #pragma unroll
    for (int t = 0; t < 5; ++t) {
        const int mask = (t == 0) ? 0 : (1 << (t - 1));
        const int s = p ^ mask;
        const float* xchunk = x  + (size_t)bm0 * INF + s * 256;
        const float* wchunk = hw + ((size_t)(t * 16 + s) * 256 + nh * 128) * 256;

        for (int k8 = 0; k8 < 8; ++k8) {
            const int kc = k8 * 32;
            #pragma unroll
            for (int i = 0; i < 4; ++i) {
                const int row = i * 32 + srow;
                float4 fa = *(const float4*)(xchunk + (size_t)row * INF + kc + scol);
                float4 fb = *(const float4*)(wchunk + (size_t)row * 256 + kc + scol);
                ushort4 ua, ub;
                ua.x = f2bf(fa.x); ua.y = f2bf(fa.y);
                ua.z = f2bf(fa.z); ua.w = f2bf(fa.w);
                ub.x = f2bf(fb.x); ub.y = f2bf(fb.y);
                ub.z = f2bf(fb.z); ub.w = f2bf(fb.w);
                *(ushort4*)&As[row][scol] = ua;
                *(ushort4*)&Bs[row][scol] = ub;
            }
            __syncthreads();

            short8 a[4], b[4];
            #pragma unroll
            for (int mi = 0; mi < 4; ++mi)
                a[mi] = *(const short8*)&As[wr * 64 + mi * 16 + (lane & 15)][(lane >> 4) * 8];
            #pragma unroll
            for (int nj = 0; nj < 4; ++nj)
                b[nj] = *(const short8*)&Bs[wc * 64 + nj * 16 + (lane & 15)][(lane >> 4) * 8];

            #pragma unroll
            for (int mi = 0; mi < 4; ++mi)
                #pragma unroll
                for (int nj = 0; nj < 4; ++nj)
                    acc[mi][nj] = __builtin_amdgcn_mfma_f32_16x16x32_bf16(
                        a[mi], b[nj], acc[mi][nj], 0, 0, 0);

            __syncthreads();
        }
    }

    const int col0 = p * 256 + nh * 128 + wc * 64;
    #pragma unroll
    for (int nj = 0; nj < 4; ++nj) {
        const int col = col0 + nj * 16 + (lane & 15);
        const float bias = hb[col];
        #pragma unroll
        for (int mi = 0; mi < 4; ++mi) {
            #pragma unroll
            for (int r = 0; r < 4; ++r) {
                const int row = bm0 + wr * 64 + mi * 16 + (lane >> 4) * 4 + r;
                out[(size_t)row * 4096 + col] = acc[mi][nj][r] + bias;
            }
        }
    }
}

extern "C" void kernel_launch(void* const* d_in, const int* in_sizes, int n_in,
                              void* d_out, int out_size, void* d_ws, size_t ws_size,
                              hipStream_t stream) {
    const float* x  = (const float*)d_in[0];   // [8192, 4096]
    const float* hw = (const float*)d_in[1];   // [5, 16, 256, 256]
    const float* hb = (const float*)d_in[2];   // [4096]
    float* out = (float*)d_out;                // [8192, 4096]

    const size_t NX = 8192ull * 4096;
    const size_t NW = 5ull * 16 * 256 * 256;
    const size_t need = (NX + NW) * sizeof(unsigned short);

    if (ws_size >= need) {
        unsigned short* xb = (unsigned short*)d_ws;
        unsigned short* wb = xb + NX;
        cvt_bf16<<<2048, 256, 0, stream>>>(x, hw, xb, wb);
        hipError_t e = hipFuncSetAttribute((const void*)hcl_gemm64,
                                           hipFuncAttributeMaxDynamicSharedMemorySize,
                                           131072);
        if (e == hipSuccess) {
            dim3 grid(8192 / 256, 16);
            hcl_gemm64<<<grid, 512, 131072, stream>>>(xb, wb, hb, out);
        } else {
            dim3 grid(8192 / 128, 16);
            hcl_gemm4<<<grid, 256, 3 * BUFB4, stream>>>(xb, wb, hb, out);
        }
    } else {
        dim3 grid(8192 / 128, 32);
        hcl_mfma_fused<<<grid, 256, 0, stream>>>(x, hw, hb, out);
    }
}